// Round 13
// baseline (157.560 us; speedup 1.0000x reference)
//
#include <hip/hip_runtime.h>

#define ALPHA 0.1f
#define NUM_CLASSES 10

typedef __attribute__((ext_vector_type(8))) short bf16x8;
typedef __attribute__((ext_vector_type(4))) float f32x4;
typedef __attribute__((ext_vector_type(2))) float f32x2;

// ---------------------------------------------------------------------------
// ws layout (bytes):
//   loss  @ 0   : float[1]
//   counts@ 4   : uint[100]
// (zeroed each launch via hipMemsetAsync)
//
// ROUND 23: R22 resubmitted unchanged -- the R22 bench died on container
// infrastructure ("MI355X container failed twice"), zero signal collected.
// The TLP->ILP experiment is still untested:
//   Evidence: VGPR_Count=64 (= persistent set: af 32 + pv 16 + c2r1 8 +
//   kidp 8) while (512,4) allows 128 -> no register window to overlap
//   pt-phases; each is a serial ~350-cycle chain and the block's waves
//   stall in correlated barrier-phases.  Eleven variants at 64 VGPR all
//   pinned at 69-75us with every pipe <50%.
//   Change: COMPUTE_HALF processes TWO pt-subtiles per iteration with
//   explicitly separate registers (both b-frag sets live, 4 independent
//   MFMA chains, both epilogues interleaved) -> allocator forced toward
//   96-128 VGPR.  Residency 3->2 blocks/CU; R15 proved wave-count
//   insensitivity; grid=512 = exactly 2 blocks/CU, 4 tiles/block, no tail.
//   Numerics: per-point op order unchanged -> u bits identical to R20/21.
//   Validity check: VGPR_Count must read 96-128; alarm = WRITE_SIZE in MB.
// ---------------------------------------------------------------------------

__device__ __forceinline__ unsigned pack2(float a, float b) {
    // (bits(b) & 0xFFFF0000) | (bits(a) >> 16)  ==  one v_perm_b32
    return __builtin_amdgcn_perm(__float_as_uint(b), __float_as_uint(a),
                                 0x07060302u);
}
__device__ __forceinline__ float truncbf(float a) {
    return __uint_as_float(__float_as_uint(a) & 0xFFFF0000u);
}
__device__ __forceinline__ unsigned packkid(float u, unsigned kid) {
    // (bits(u) & 0xFFFFFF00) | kid  ==  one v_perm_b32 (kid < 256)
    return __builtin_amdgcn_perm(__float_as_uint(u), kid, 0x07060500u);
}

// stage: convert this wave's prefetched 16-pt subtile into buffer BUF slot
// SUB; write x2; reload pv with tile TNEXT's rows (if valid).
#define STAGE_HALF(BUF, SUB, TNEXT)                                           \
    {                                                                         \
        float4 v0 = pv0, v1 = pv1, v2 = pv2, v3 = pv3;                        \
        if ((TNEXT) < NT) {                                                   \
            const int row_ = (TNEXT) * 128 + w * 16 + r;                      \
            const float4* X_ = (const float4*)(x + (size_t)row_ * 64);        \
            pv0 = X_[q * 2]; pv1 = X_[q * 2 + 1];                             \
            pv2 = X_[8 + q * 2]; pv3 = X_[9 + q * 2];                         \
        }                                                                     \
        float p = v0.x * v0.x;                                                \
        p = fmaf(v0.y, v0.y, p); p = fmaf(v0.z, v0.z, p); p = fmaf(v0.w, v0.w, p); \
        p = fmaf(v1.x, v1.x, p); p = fmaf(v1.y, v1.y, p); p = fmaf(v1.z, v1.z, p); p = fmaf(v1.w, v1.w, p); \
        p = fmaf(v2.x, v2.x, p); p = fmaf(v2.y, v2.y, p); p = fmaf(v2.z, v2.z, p); p = fmaf(v2.w, v2.w, p); \
        p = fmaf(v3.x, v3.x, p); p = fmaf(v3.y, v3.y, p); p = fmaf(v3.z, v3.z, p); p = fmaf(v3.w, v3.w, p); \
        p += __shfl_xor(p, 16);                                               \
        p += __shfl_xor(p, 32);                                               \
        if (q == 0) x2s[BUF][(SUB) * 16 + r] = p;                             \
        union { bf16x8 v; uint4 u4; unsigned u[4]; } h0, h1, l0, l1;          \
        h0.u[0] = pack2(v0.x, v0.y); h0.u[1] = pack2(v0.z, v0.w);             \
        h0.u[2] = pack2(v1.x, v1.y); h0.u[3] = pack2(v1.z, v1.w);             \
        h1.u[0] = pack2(v2.x, v2.y); h1.u[1] = pack2(v2.z, v2.w);             \
        h1.u[2] = pack2(v3.x, v3.y); h1.u[3] = pack2(v3.z, v3.w);             \
        l0.u[0] = pack2(v0.x - truncbf(v0.x), v0.y - truncbf(v0.y));          \
        l0.u[1] = pack2(v0.z - truncbf(v0.z), v0.w - truncbf(v0.w));          \
        l0.u[2] = pack2(v1.x - truncbf(v1.x), v1.y - truncbf(v1.y));          \
        l0.u[3] = pack2(v1.z - truncbf(v1.z), v1.w - truncbf(v1.w));          \
        l1.u[0] = pack2(v2.x - truncbf(v2.x), v2.y - truncbf(v2.y));          \
        l1.u[1] = pack2(v2.z - truncbf(v2.z), v2.w - truncbf(v2.w));          \
        l1.u[2] = pack2(v3.x - truncbf(v3.x), v3.y - truncbf(v3.y));          \
        l1.u[3] = pack2(v3.z - truncbf(v3.z), v3.w - truncbf(v3.w));          \
        *(uint4*)(bstage + ((((BUF) * 16 + (SUB) * 4 + 0) * 64 + lane) << 4)) = h0.u4; \
        *(uint4*)(bstage + ((((BUF) * 16 + (SUB) * 4 + 1) * 64 + lane) << 4)) = h1.u4; \
        *(uint4*)(bstage + ((((BUF) * 16 + (SUB) * 4 + 2) * 64 + lane) << 4)) = l0.u4; \
        *(uint4*)(bstage + ((((BUF) * 16 + (SUB) * 4 + 3) * 64 + lane) << 4)) = l1.u4; \
    }

// 6-MFMA split-bf16 chain for one (ct, pt) pair
#define MFMA_CHAIN(A, CT, B0, B1, B2, B3)                                     \
    A = __builtin_amdgcn_mfma_f32_16x16x32_bf16(af[CT][0], B0.v, A, 0, 0, 0); \
    A = __builtin_amdgcn_mfma_f32_16x16x32_bf16(af[CT][1], B1.v, A, 0, 0, 0); \
    A = __builtin_amdgcn_mfma_f32_16x16x32_bf16(af[CT][2], B0.v, A, 0, 0, 0); \
    A = __builtin_amdgcn_mfma_f32_16x16x32_bf16(af[CT][3], B1.v, A, 0, 0, 0); \
    A = __builtin_amdgcn_mfma_f32_16x16x32_bf16(af[CT][0], B2.v, A, 0, 0, 0); \
    A = __builtin_amdgcn_mfma_f32_16x16x32_bf16(af[CT][1], B3.v, A, 0, 0, 0);

// epilogue for one pt's acc pair -> swe/swdu/best (R20's packed math)
#define EPILOGUE(ACC, SWE, SWDU, BEST)                                        \
    {                                                                         \
        BEST = 0xFFFFFFFFu;                                                   \
        f32x2 swe2 = {0.f, 0.f}, swd2 = {0.f, 0.f};                           \
        _Pragma("unroll")                                                     \
        for (int ct = 0; ct < 2; ++ct) {                                      \
            const float u0 = ACC[ct][0], u1 = ACC[ct][1];                     \
            const float u2 = ACC[ct][2], u3 = ACC[ct][3];                     \
            const unsigned p0 = packkid(u0, kidp[ct][0]);                     \
            const unsigned p1 = packkid(u1, kidp[ct][1]);                     \
            const unsigned p2 = packkid(u2, kidp[ct][2]);                     \
            const unsigned p3 = packkid(u3, kidp[ct][3]);                     \
            BEST = min(BEST, min(min(p0, p1), min(p2, p3)));                  \
            f32x2 m01, m23;                                                   \
            m01[0] = __log2f(u0); m01[1] = __log2f(u1);                       \
            m23[0] = __log2f(u2); m23[1] = __log2f(u3);                       \
            const f32x2 na = {-ALPHA, -ALPHA};                                \
            m01 = m01 * na;                                                   \
            m23 = m23 * na;                                                   \
            f32x2 w01, w23, u01, u23;                                         \
            w01[0] = exp2f(m01[0]); w01[1] = exp2f(m01[1]);                   \
            w23[0] = exp2f(m23[0]); w23[1] = exp2f(m23[1]);                   \
            u01[0] = u0; u01[1] = u1;                                         \
            u23[0] = u2; u23[1] = u3;                                         \
            swe2 = swe2 + (w01 + w23);                                        \
            swd2 = __builtin_elementwise_fma(w01, u01, swd2);                 \
            swd2 = __builtin_elementwise_fma(w23, u23, swd2);                 \
        }                                                                     \
        SWE  = swe2[0] + swe2[1];                                             \
        SWDU = swd2[0] + swd2[1];                                             \
    }

// compute: all 8 waves, 4 subtiles of buffer BUF, processed as TWO
// dual-pt iterations.  Both pt's b-frags/accs live simultaneously ->
// 4 independent MFMA chains + 2 interleaved epilogues per iteration.
#define COMPUTE_HALF(BUF)                                                     \
    _Pragma("unroll")                                                         \
    for (int pp = 0; pp < 2; ++pp) {                                          \
        const int pA = pp * 2, pB = pp * 2 + 1;                               \
        union { uint4 u4; bf16x8 v; } a0, a1, a2, a3, c0, c1, c2, c3;         \
        a0.u4 = *(const uint4*)(bstage + ((((BUF) * 16 + pA * 4 + 0) * 64 + lane) << 4)); \
        a1.u4 = *(const uint4*)(bstage + ((((BUF) * 16 + pA * 4 + 1) * 64 + lane) << 4)); \
        a2.u4 = *(const uint4*)(bstage + ((((BUF) * 16 + pA * 4 + 2) * 64 + lane) << 4)); \
        a3.u4 = *(const uint4*)(bstage + ((((BUF) * 16 + pA * 4 + 3) * 64 + lane) << 4)); \
        c0.u4 = *(const uint4*)(bstage + ((((BUF) * 16 + pB * 4 + 0) * 64 + lane) << 4)); \
        c1.u4 = *(const uint4*)(bstage + ((((BUF) * 16 + pB * 4 + 1) * 64 + lane) << 4)); \
        c2.u4 = *(const uint4*)(bstage + ((((BUF) * 16 + pB * 4 + 2) * 64 + lane) << 4)); \
        c3.u4 = *(const uint4*)(bstage + ((((BUF) * 16 + pB * 4 + 3) * 64 + lane) << 4)); \
        const float xA = x2s[BUF][pA * 16 + r];                               \
        const float xB = x2s[BUF][pB * 16 + r];                               \
        const f32x4 xvA = {xA, xA, xA, xA};                                   \
        const f32x4 xvB = {xB, xB, xB, xB};                                   \
        f32x4 accA[2], accB[2];                                               \
        _Pragma("unroll")                                                     \
        for (int ct = 0; ct < 2; ++ct) {                                      \
            f32x4 aa = xvA + c2r1v[ct];                                       \
            f32x4 bb = xvB + c2r1v[ct];                                       \
            MFMA_CHAIN(aa, ct, a0, a1, a2, a3);                               \
            MFMA_CHAIN(bb, ct, c0, c1, c2, c3);                               \
            accA[ct] = aa; accB[ct] = bb;                                     \
        }                                                                     \
        float sweA, swdA, sweB, swdB;                                         \
        unsigned bestA, bestB;                                                \
        EPILOGUE(accA, sweA, swdA, bestA);                                    \
        EPILOGUE(accB, sweB, swdB, bestB);                                    \
        sweA += __shfl_xor(sweA, 16); sweB += __shfl_xor(sweB, 16);           \
        sweA += __shfl_xor(sweA, 32); sweB += __shfl_xor(sweB, 32);           \
        swdA += __shfl_xor(swdA, 16); swdB += __shfl_xor(swdB, 16);           \
        swdA += __shfl_xor(swdA, 32); swdB += __shfl_xor(swdB, 32);           \
        bestA = min(bestA, (unsigned)__shfl_xor((int)bestA, 16));             \
        bestB = min(bestB, (unsigned)__shfl_xor((int)bestB, 16));             \
        bestA = min(bestA, (unsigned)__shfl_xor((int)bestA, 32));             \
        bestB = min(bestB, (unsigned)__shfl_xor((int)bestB, 32));             \
        if (q == 0) {                                                         \
            comb_swe[BUF][w][pA * 16 + r]  = sweA;                            \
            comb_swd[BUF][w][pA * 16 + r]  = swdA;                            \
            comb_best[BUF][w][pA * 16 + r] = bestA;                           \
            comb_swe[BUF][w][pB * 16 + r]  = sweB;                            \
            comb_swd[BUF][w][pB * 16 + r]  = swdB;                            \
            comb_best[BUF][w][pB * 16 + r] = bestB;                           \
        }                                                                     \
    }

// combine: one wave (64 lanes = 64 points of the half) folds the 8 groups.
#define COMBINE_HALF(BUF, YL)                                                 \
    {                                                                         \
        float SWE = comb_swe[BUF][0][lane], SWD = comb_swd[BUF][0][lane];     \
        unsigned BEST = comb_best[BUF][0][lane];                              \
        _Pragma("unroll")                                                     \
        for (int g = 1; g < 8; ++g) {                                         \
            SWE += comb_swe[BUF][g][lane];                                    \
            SWD += comb_swd[BUF][g][lane];                                    \
            BEST = min(BEST, comb_best[BUF][g][lane]);                        \
        }                                                                     \
        loss_local += SWD / SWE - 1.f;                                        \
        const unsigned bk = BEST & 0xFFu;                                     \
        if (bk < NUM_CLASSES) {                                               \
            atomicAdd(&counts_l[bk * NUM_CLASSES + (YL)], 1u);                \
        }                                                                     \
    }

// 512 threads = 8 waves.  Wave w owns centers [w*32, w*32+32) (M dim) and
// stages points [t*128 + w*16, +16): quad0 (w<4) = even halves (pts 0-63),
// quad1 = odd halves (pts 64-127).  Lane: r = l&15, q = l>>4.
__global__ __launch_bounds__(512, 4) void dist_kernel(
    const float* __restrict__ x,
    const int*   __restrict__ y,
    const float* __restrict__ centers,
    float* __restrict__ loss_acc,
    unsigned int* __restrict__ counts,
    int NT)
{
    __shared__ __align__(16) char bstage[2 * 16 * 64 * 16];   // 32 KB, 2 bufs
    __shared__ float x2s[2][64];
    __shared__ float c2s[256];
    __shared__ float    comb_swe[2][8][64];    // 4 KB
    __shared__ float    comb_swd[2][8][64];    // 4 KB
    __shared__ unsigned comb_best[2][8][64];   // 4 KB
    __shared__ unsigned counts_l[100];

    const int tid  = threadIdx.x;
    const int w    = tid >> 6;
    const int lane = tid & 63;
    const int q    = lane >> 4;
    const int r    = lane & 15;

    if (tid < 100) counts_l[tid] = 0u;

    // ---- startup: center norms (one center per thread) ----
    if (tid < 256) {
        const float4* crow = (const float4*)(centers + tid * 64);
        float s = 0.f;
#pragma unroll
        for (int j = 0; j < 16; ++j) {
            float4 v = crow[j];
            s = fmaf(v.x, v.x, s); s = fmaf(v.y, v.y, s);
            s = fmaf(v.z, v.z, s); s = fmaf(v.w, v.w, s);
        }
        c2s[tid] = s;
    }

    // ---- startup: this wave's center A-frags, PRE-SCALED by -2 ----
    bf16x8 af[2][4];
#pragma unroll
    for (int ct = 0; ct < 2; ++ct) {
        const int row = w * 32 + ct * 16 + r;
        const float4* C = (const float4*)(centers + (size_t)row * 64);
        float4 v0 = C[q * 2], v1 = C[q * 2 + 1];
        float4 v2 = C[8 + q * 2], v3 = C[9 + q * 2];
        float4 m0 = make_float4(-2.f * v0.x, -2.f * v0.y, -2.f * v0.z, -2.f * v0.w);
        float4 m1 = make_float4(-2.f * v1.x, -2.f * v1.y, -2.f * v1.z, -2.f * v1.w);
        float4 m2 = make_float4(-2.f * v2.x, -2.f * v2.y, -2.f * v2.z, -2.f * v2.w);
        float4 m3 = make_float4(-2.f * v3.x, -2.f * v3.y, -2.f * v3.z, -2.f * v3.w);
        union { bf16x8 v; unsigned u[4]; } h0, h1, l0, l1;
        h0.u[0] = pack2(m0.x, m0.y); h0.u[1] = pack2(m0.z, m0.w);
        h0.u[2] = pack2(m1.x, m1.y); h0.u[3] = pack2(m1.z, m1.w);
        h1.u[0] = pack2(m2.x, m2.y); h1.u[1] = pack2(m2.z, m2.w);
        h1.u[2] = pack2(m3.x, m3.y); h1.u[3] = pack2(m3.z, m3.w);
        l0.u[0] = pack2(m0.x - truncbf(m0.x), m0.y - truncbf(m0.y));
        l0.u[1] = pack2(m0.z - truncbf(m0.z), m0.w - truncbf(m0.w));
        l0.u[2] = pack2(m1.x - truncbf(m1.x), m1.y - truncbf(m1.y));
        l0.u[3] = pack2(m1.z - truncbf(m1.z), m1.w - truncbf(m1.w));
        l1.u[0] = pack2(m2.x - truncbf(m2.x), m2.y - truncbf(m2.y));
        l1.u[1] = pack2(m2.z - truncbf(m2.z), m2.w - truncbf(m2.w));
        l1.u[2] = pack2(m3.x - truncbf(m3.x), m3.y - truncbf(m3.y));
        l1.u[3] = pack2(m3.z - truncbf(m3.z), m3.w - truncbf(m3.w));
        af[ct][0] = h0.v; af[ct][1] = h1.v; af[ct][2] = l0.v; af[ct][3] = l1.v;
    }

    // ---- startup: per-lane argmin kid bytes (persistent, for v_perm) ----
    unsigned kidp[2][4];
#pragma unroll
    for (int ct = 0; ct < 2; ++ct)
#pragma unroll
        for (int reg = 0; reg < 4; ++reg)
            kidp[ct][reg] = (unsigned)(w * 32 + ct * 16 + q * 4 + reg);

    // ---- prefetch tile t0's x rows (every wave: its own 16-pt subtile) ----
    const int G  = gridDim.x;
    const int t0 = blockIdx.x;
    float4 pv0, pv1, pv2, pv3;
    {
        const int row = t0 * 128 + w * 16 + r;
        const float4* X = (const float4*)(x + (size_t)row * 64);
        pv0 = X[q * 2]; pv1 = X[q * 2 + 1];
        pv2 = X[8 + q * 2]; pv3 = X[9 + q * 2];
    }

    // ---- prologue: quad0 stages half(t0,0) into buf0 ----
    if (w < 4) STAGE_HALF(0, w, t0 + G);

    __syncthreads();   // c2s + buf0 + x2s[0] + counts_l visible

    // this lane's 8 center norms + 1 (f32x4 for packed acc-init)
    f32x4 c2r1v[2];
#pragma unroll
    for (int ct = 0; ct < 2; ++ct) {
        const float4 v = *(const float4*)(c2s + w * 32 + ct * 16 + q * 4);
        f32x4 t; t[0] = v.x + 1.f; t[1] = v.y + 1.f;
        t[2] = v.z + 1.f; t[3] = v.w + 1.f;
        c2r1v[ct] = t;
    }

    float loss_local = 0.f;
    int have_prev = 0;
    int t = t0;
    for (; t < NT; t += G) {
        // ---- body A: stage half(t,1)[quad1] || compute half(t,0)[all]
        //              || combine half(t-G,1)[wave 0] ----
        int yA = 0;
        if (w == 0 && have_prev) yA = y[(t - G) * 128 + 64 + lane];
        if (w >= 4) STAGE_HALF(1, w - 4, t + G);
        COMPUTE_HALF(0);
        if (w == 0 && have_prev) COMBINE_HALF(1, yA);
        __syncthreads();   // buf1+x2s[1] staged; comb[0] full; comb[1] free

        // ---- body B: stage half(t+G,0)[quad0] || compute half(t,1)[all]
        //              || combine half(t,0)[wave 7] ----
        int yB = 0;
        if (w == 7) yB = y[t * 128 + lane];
        if (w < 4 && (t + G) < NT) STAGE_HALF(0, w, t + 2 * G);
        COMPUTE_HALF(1);
        if (w == 7) COMBINE_HALF(0, yB);
        __syncthreads();   // buf0(next) staged; comb[1] full; comb[0] free

        have_prev = 1;
    }

    // ---- drain: combine the final odd half (t_last,1) ----
    if (w == 0) {
        const int tl = t - G;
        const int yD = y[tl * 128 + 64 + lane];
        COMBINE_HALF(1, yD);
    }

    // loss lives on waves 0 and 7 only
    if (w == 0 || w == 7) {
        float v = loss_local;
#pragma unroll
        for (int o = 32; o > 0; o >>= 1) v += __shfl_down(v, o);
        if (lane == 0) atomicAdd(loss_acc, v);
    }

    __syncthreads();
    if (tid < 100) {
        const unsigned c = counts_l[tid];
        if (c) atomicAdd(&counts[tid], c);
    }
}

// ---------------------------------------------------------------------------
// Finalize: greedy cluster->label assignment, exactly mirroring the reference.
// Counts loaded by 100 parallel threads.
// ---------------------------------------------------------------------------

__global__ void finalize_kernel(
    const float* __restrict__ loss_acc,
    const unsigned int* __restrict__ counts,
    float* __restrict__ out,
    int N)
{
    __shared__ float cs[NUM_CLASSES * NUM_CLASSES];
    __shared__ float ls;
    const int tid = threadIdx.x;
    if (tid < NUM_CLASSES * NUM_CLASSES) cs[tid] = (float)counts[tid];
    if (tid == NUM_CLASSES * NUM_CLASSES) ls = loss_acc[0];
    __syncthreads();
    if (tid == 0) {
        bool used[NUM_CLASSES];
        for (int i = 0; i < NUM_CLASSES; ++i) used[i] = false;

        float correct = 0.f;
        for (int i = 0; i < NUM_CLASSES; ++i) {
            const float* ci = cs + i * NUM_CLASSES;
            float rowsum = 0.f;
            for (int j = 0; j < NUM_CLASSES; ++j) rowsum += ci[j];
            bool has_points = rowsum > 0.f;

            int label = 0;
            float mx = ci[0];
            for (int j = 1; j < NUM_CLASSES; ++j)
                if (ci[j] > mx) { mx = ci[j]; label = j; }

            if (used[label]) {
                float mm = used[0] ? 0.f : ci[0];
                int l2 = 0;
                for (int j = 1; j < NUM_CLASSES; ++j) {
                    float v = used[j] ? 0.f : ci[j];
                    if (v > mm) { mm = v; l2 = j; }
                }
                label = l2;
            }

            if (has_points) {
                correct += ci[label];
                used[label] = true;
            }
        }
        out[0] = ls;
        out[1] = correct / (float)N;
    }
}

// ---------------------------------------------------------------------------

extern "C" void kernel_launch(void* const* d_in, const int* in_sizes, int n_in,
                              void* d_out, int out_size, void* d_ws, size_t ws_size,
                              hipStream_t stream)
{
    const float* x       = (const float*)d_in[0];
    const int*   y       = (const int*)d_in[1];
    const float* centers = (const float*)d_in[2];
    float* out = (float*)d_out;

    const int N  = in_sizes[0] / 64;  // D = 64
    const int NT = N / 128;           // 128-point tiles

    float* loss          = (float*)d_ws;                       // 4 B
    unsigned int* counts = (unsigned int*)((char*)d_ws + 4);   // 400 B

    hipMemsetAsync(d_ws, 0, 512, stream);

    // grid = 512 = exactly 2 blocks/CU at the expected ~100-128 VGPR
    // allocation (m69: >64 VGPR -> 4 waves/SIMD -> 16 waves/CU).
    // 4 tiles/block, zero dispatch tail.
    int grid = 512;
    if (grid > NT) grid = NT;
    dist_kernel<<<grid, 512, 0, stream>>>(x, y, centers, loss, counts, NT);

    finalize_kernel<<<1, 128, 0, stream>>>(loss, counts, out, N);
}